// Round 8
// baseline (134.204 us; speedup 1.0000x reference)
//
#include <hip/hip_runtime.h>
#include <stdint.h>

#define BATCH 32
#define CH    256
#define TLEN  4096
#define TN    64

typedef short    bf16x8 __attribute__((ext_vector_type(8)));
typedef float    f32x4  __attribute__((ext_vector_type(4)));
typedef uint16_t u16x4  __attribute__((ext_vector_type(4)));

__device__ __attribute__((aligned(16))) uint16_t g_w1eff[CH * CH];
__device__ __attribute__((aligned(16))) float g_tap[5 * CH];   // tap-major: g_tap[j*CH + c]
__device__ __attribute__((aligned(16))) float g_bias[CH];

static __device__ __forceinline__ uint16_t f32_to_bf16(float f) {
    uint32_t u = __builtin_bit_cast(uint32_t, f);
    u += 0x7FFFu + ((u >> 16) & 1u);
    return (uint16_t)(u >> 16);
}
static __device__ __forceinline__ float bf16_to_f32(uint16_t h) {
    uint32_t u = ((uint32_t)h) << 16;
    return __builtin_bit_cast(float, u);
}
// tanh-form gelu folded into exp2: gelu ~= x - x / (1 + 2^(x*(A + B*x^2)))
// A = 2*0.7978845608*log2(e), B = A*0.044715. Max abs err vs exact-erf ~3e-3.
static __device__ __forceinline__ float gelu_fast(float x) {
    const float A = 2.3022082f;
    const float B = 0.10294331f;
    float x2 = x * x;
    float z  = x * fmaf(x2, B, A);
    float e  = exp2f(z);                        // v_exp_f32
    float r  = __builtin_amdgcn_rcpf(1.0f + e); // v_rcp_f32
    return fmaf(-x, r, x);
}

// Precompute: w1eff[o][c] = wc0[o]*w1[o][c] (bf16); 5-tap g (tap-major); fused bias.
__global__ void prep_kernel(const float* __restrict__ w1, const float* __restrict__ b1,
                            const float* __restrict__ w3, const float* __restrict__ b3,
                            const float* __restrict__ w5, const float* __restrict__ b5,
                            const float* __restrict__ wc, const float* __restrict__ bc) {
    const int o = blockIdx.x;
    const int c = threadIdx.x;
    const float wc0 = wc[o * 3 + 0];
    g_w1eff[o * CH + c] = f32_to_bf16(wc0 * w1[o * CH + c]);
    if (c == 0) {
        const float wc1 = wc[o * 3 + 1], wc2 = wc[o * 3 + 2];
        g_tap[0 * CH + o] = wc2 * w5[o * 5 + 0];
        g_tap[1 * CH + o] = wc1 * w3[o * 3 + 0] + wc2 * w5[o * 5 + 1];
        g_tap[2 * CH + o] = wc1 * w3[o * 3 + 1] + wc2 * w5[o * 5 + 2];
        g_tap[3 * CH + o] = wc1 * w3[o * 3 + 2] + wc2 * w5[o * 5 + 3];
        g_tap[4 * CH + o] = wc2 * w5[o * 5 + 4];
        g_bias[o] = wc0 * b1[o] + wc1 * b3[o] + wc2 * b5[o] + bc[o];
    }
}

// Per block = one (batch b, 64-timestep tile).
// sA: gelu(x) tile [t=0..67][c=0..255] bf16, t-major, XOR-swizzled.
// After the GEMM + in-register depthwise fold, sA's storage is REUSED as the
// per-wave f32 transpose scratch (wave-private 16x68 region, no barriers).
__global__ __launch_bounds__(256, 4)
void fused_kernel(const float* __restrict__ x, float* __restrict__ out) {
    __shared__ __attribute__((aligned(16))) uint16_t sA[68 * CH];   // 34816 B

    const int tid  = threadIdx.x;
    const int lane = tid & 63;
    const int wid  = tid >> 6;
    const int b    = blockIdx.y;
    const int t0   = blockIdx.x * TN;

    const float* __restrict__ xb = x + (size_t)b * CH * TLEN;

    // ---- main staging pass: rows ti = 0..63 (gt = t0-2+lane) ----
    {
        const int gt = t0 - 2 + lane;
        const int c0 = wid * 64;
        if (blockIdx.x > 0) {   // interior: gt in [62, 4093]
#pragma unroll
            for (int g = 0; g < 8; ++g) {
                const int cb = c0 + g * 8;
                const float* xp = xb + (size_t)cb * TLEN + gt;
                bf16x8 pk;
#pragma unroll
                for (int j = 0; j < 8; ++j)
                    pk[j] = (short)f32_to_bf16(gelu_fast(xp[(size_t)j * TLEN]));
                *(bf16x8*)(&sA[lane * CH + (cb ^ ((lane & 7) << 3))]) = pk;
            }
        } else {                // first tile: gt may be -2,-1
#pragma unroll
            for (int g = 0; g < 8; ++g) {
                const int cb = c0 + g * 8;
                const float* xp = xb + (size_t)cb * TLEN + gt;
                bf16x8 pk;
#pragma unroll
                for (int j = 0; j < 8; ++j) {
                    float v = (gt >= 0) ? xp[(size_t)j * TLEN] : 0.0f;
                    pk[j] = (short)f32_to_bf16(gelu_fast(v));
                }
                *(bf16x8*)(&sA[lane * CH + (cb ^ ((lane & 7) << 3))]) = pk;
            }
        }
    }
    // ---- halo pass: rows ti = 64..67 (gt = t0+62..t0+65), c = tid ----
    {
        const int c = tid;
        if (blockIdx.x < gridDim.x - 1) {
#pragma unroll
            for (int k = 0; k < 4; ++k) {
                float v = xb[(size_t)c * TLEN + (t0 + 62 + k)];
                sA[(64 + k) * CH + (c ^ (k << 3))] = f32_to_bf16(gelu_fast(v));
            }
        } else {
#pragma unroll
            for (int k = 0; k < 4; ++k) {
                const int gt = t0 + 62 + k;
                float v = (gt < TLEN) ? xb[(size_t)c * TLEN + gt] : 0.0f;
                sA[(64 + k) * CH + (c ^ (k << 3))] = f32_to_bf16(gelu_fast(v));
            }
        }
    }
    __syncthreads();

    f32x4 acc[4][4];
    const f32x4 vzero = {0.f, 0.f, 0.f, 0.f};
#pragma unroll
    for (int mi = 0; mi < 4; ++mi)
#pragma unroll
        for (int ni = 0; ni < 4; ++ni) acc[mi][ni] = vzero;

    const int m0   = wid * 64;
    const int kgrp = (lane >> 4) * 8;  // k sub-offset per 16-lane group

    // Barrier-free K loop: weight fragments from global (L2), activations from LDS.
#pragma unroll
    for (int kk = 0; kk < CH; kk += 32) {
        bf16x8 af[4], bfr[4];
#pragma unroll
        for (int mi = 0; mi < 4; ++mi) {
            const int co = m0 + mi * 16 + (lane & 15);
            af[mi] = *(const bf16x8*)(g_w1eff + co * CH + kk + kgrp);
        }
        const int cin = kk + kgrp;
#pragma unroll
        for (int ni = 0; ni < 4; ++ni) {
            const int tr = ni * 16 + (lane & 15) + 2;  // sA row for t = ni*16+(lane&15)
            bfr[ni] = *(const bf16x8*)(&sA[tr * CH + (cin ^ ((tr & 7) << 3))]);
        }
#pragma unroll
        for (int mi = 0; mi < 4; ++mi)
#pragma unroll
            for (int ni = 0; ni < 4; ++ni)
                acc[mi][ni] = __builtin_amdgcn_mfma_f32_16x16x32_bf16(af[mi], bfr[ni], acc[mi][ni], 0, 0, 0);
    }

    // Epilogue phase A: fold depthwise + bias into acc (in-register).
    // MFMA D layout: col(t) = lane&15, row(c) = (lane>>4)*4 + reg.
    const int colt = lane & 15;
    const int rg   = (lane >> 4) * 4;
#pragma unroll
    for (int mi = 0; mi < 4; ++mi) {
        const int c = m0 + mi * 16 + rg;           // 4 channels c..c+3, 4-aligned
        const f32x4 tp0 = *(const f32x4*)(g_tap + 0 * CH + c);
        const f32x4 tp1 = *(const f32x4*)(g_tap + 1 * CH + c);
        const f32x4 tp2 = *(const f32x4*)(g_tap + 2 * CH + c);
        const f32x4 tp3 = *(const f32x4*)(g_tap + 3 * CH + c);
        const f32x4 tp4 = *(const f32x4*)(g_tap + 4 * CH + c);
        const f32x4 bsv = *(const f32x4*)(g_bias + c);
#pragma unroll
        for (int ni = 0; ni < 4; ++ni) {
            const int t = ni * 16 + colt;          // tile-local time
            u16x4 a0 = *(const u16x4*)(&sA[(t + 0) * CH + (c ^ (((t + 0) & 7) << 3))]);
            u16x4 a1 = *(const u16x4*)(&sA[(t + 1) * CH + (c ^ (((t + 1) & 7) << 3))]);
            u16x4 a2 = *(const u16x4*)(&sA[(t + 2) * CH + (c ^ (((t + 2) & 7) << 3))]);
            u16x4 a3 = *(const u16x4*)(&sA[(t + 3) * CH + (c ^ (((t + 3) & 7) << 3))]);
            u16x4 a4 = *(const u16x4*)(&sA[(t + 4) * CH + (c ^ (((t + 4) & 7) << 3))]);
#pragma unroll
            for (int r = 0; r < 4; ++r) {
                float d = tp0[r] * bf16_to_f32(a0[r]);
                d = fmaf(tp1[r], bf16_to_f32(a1[r]), d);
                d = fmaf(tp2[r], bf16_to_f32(a2[r]), d);
                d = fmaf(tp3[r], bf16_to_f32(a3[r]), d);
                d = fmaf(tp4[r], bf16_to_f32(a4[r]), d);
                acc[mi][ni][r] += d + bsv[r];
            }
        }
    }
    __syncthreads();   // all sA reads done block-wide; sA becomes f32 scratch

    // Epilogue phase B: wave-private transpose through sA's storage (no barriers).
    float* __restrict__ sS = ((float*)sA) + wid * (16 * 68);   // 4.25 KB per wave
    float* __restrict__ ob = out + (size_t)b * CH * TLEN;
    const int ci = lane >> 2;          // 0..15 channel-local
    const int q  = lane & 3;           // 0..3 t-quad (16 t each)

#pragma unroll
    for (int mi = 0; mi < 4; ++mi) {
#pragma unroll
        for (int ni = 0; ni < 4; ++ni) {
            const int t = ni * 16 + colt;
#pragma unroll
            for (int r = 0; r < 4; ++r) sS[(rg + r) * 68 + t] = acc[mi][ni][r];
        }
        const int cc = m0 + mi * 16 + ci;
        const float* xrow = xb + (size_t)cc * TLEN + t0 + q * 16;
        float*       orow = ob + (size_t)cc * TLEN + t0 + q * 16;
        f32x4 xv0 = *(const f32x4*)(xrow + 0);
        f32x4 xv1 = *(const f32x4*)(xrow + 4);
        f32x4 xv2 = *(const f32x4*)(xrow + 8);
        f32x4 xv3 = *(const f32x4*)(xrow + 12);
        const float* srow = sS + ci * 68 + q * 16;
        f32x4 s0 = *(const f32x4*)(srow + 0);
        f32x4 s1 = *(const f32x4*)(srow + 4);
        f32x4 s2 = *(const f32x4*)(srow + 8);
        f32x4 s3 = *(const f32x4*)(srow + 12);
        *(f32x4*)(orow + 0)  = s0 + xv0;
        *(f32x4*)(orow + 4)  = s1 + xv1;
        *(f32x4*)(orow + 8)  = s2 + xv2;
        *(f32x4*)(orow + 12) = s3 + xv3;
    }
}

extern "C" void kernel_launch(void* const* d_in, const int* in_sizes, int n_in,
                              void* d_out, int out_size, void* d_ws, size_t ws_size,
                              hipStream_t stream) {
    const float* x  = (const float*)d_in[0];
    const float* w1 = (const float*)d_in[1];
    const float* b1 = (const float*)d_in[2];
    const float* w3 = (const float*)d_in[3];
    const float* b3 = (const float*)d_in[4];
    const float* w5 = (const float*)d_in[5];
    const float* b5 = (const float*)d_in[6];
    const float* wc = (const float*)d_in[7];
    const float* bc = (const float*)d_in[8];
    float* out = (float*)d_out;

    prep_kernel<<<dim3(CH), dim3(CH), 0, stream>>>(w1, b1, w3, b3, w5, b5, wc, bc);
    fused_kernel<<<dim3(TLEN / TN, BATCH), dim3(256), 0, stream>>>(x, out);
}

// Round 9
// 129.774 us; speedup vs baseline: 1.0341x; 1.0341x over previous
//
#include <hip/hip_runtime.h>
#include <stdint.h>

#define BATCH 32
#define CH    256
#define TLEN  4096
#define TN    64
#define SXS   72   // sX row stride in u16 (144 B, 16B-aligned)

typedef short    bf16x8 __attribute__((ext_vector_type(8)));
typedef float    f32x4  __attribute__((ext_vector_type(4)));
typedef uint16_t u16x4  __attribute__((ext_vector_type(4)));
typedef uint16_t u16x8  __attribute__((ext_vector_type(8)));

__device__ __attribute__((aligned(16))) uint16_t g_w1eff[CH * CH];
__device__ __attribute__((aligned(16))) float g_tap[5 * CH];   // tap-major: g_tap[j*CH + c]
__device__ __attribute__((aligned(16))) float g_bias[CH];

static __device__ __forceinline__ uint16_t f32_to_bf16(float f) {
    uint32_t u = __builtin_bit_cast(uint32_t, f);
    u += 0x7FFFu + ((u >> 16) & 1u);
    return (uint16_t)(u >> 16);
}
static __device__ __forceinline__ float bf16_to_f32(uint16_t h) {
    uint32_t u = ((uint32_t)h) << 16;
    return __builtin_bit_cast(float, u);
}
// tanh-form gelu folded into exp2: gelu ~= x - x / (1 + 2^(x*(A + B*x^2)))
static __device__ __forceinline__ float gelu_fast(float x) {
    const float A = 2.3022082f;
    const float B = 0.10294331f;
    float x2 = x * x;
    float z  = x * fmaf(x2, B, A);
    float e  = exp2f(z);                        // v_exp_f32
    float r  = __builtin_amdgcn_rcpf(1.0f + e); // v_rcp_f32
    return fmaf(-x, r, x);
}

// Precompute: w1eff[o][c] = wc0[o]*w1[o][c] (bf16); 5-tap g (tap-major); fused bias.
__global__ void prep_kernel(const float* __restrict__ w1, const float* __restrict__ b1,
                            const float* __restrict__ w3, const float* __restrict__ b3,
                            const float* __restrict__ w5, const float* __restrict__ b5,
                            const float* __restrict__ wc, const float* __restrict__ bc) {
    const int o = blockIdx.x;
    const int c = threadIdx.x;
    const float wc0 = wc[o * 3 + 0];
    g_w1eff[o * CH + c] = f32_to_bf16(wc0 * w1[o * CH + c]);
    if (c == 0) {
        const float wc1 = wc[o * 3 + 1], wc2 = wc[o * 3 + 2];
        g_tap[0 * CH + o] = wc2 * w5[o * 5 + 0];
        g_tap[1 * CH + o] = wc1 * w3[o * 3 + 0] + wc2 * w5[o * 5 + 1];
        g_tap[2 * CH + o] = wc1 * w3[o * 3 + 1] + wc2 * w5[o * 5 + 2];
        g_tap[3 * CH + o] = wc1 * w3[o * 3 + 2] + wc2 * w5[o * 5 + 3];
        g_tap[4 * CH + o] = wc2 * w5[o * 5 + 4];
        g_bias[o] = wc0 * b1[o] + wc1 * b3[o] + wc2 * b5[o] + bc[o];
    }
}

// Per block = one (batch b, 64-timestep tile).
// sA: gelu(x) [t=0..67][c] bf16, t-major, XOR-swizzled (GEMM B-operand + taps).
// sX: bf16(x) [c][t=0..63] c-major (residual; read back vectorized in epilogue).
// K-loop: 1-deep software pipeline (ping-pong af/bf fragment buffers).
// After phase A, sA's storage is reused as per-wave f32 transpose scratch.
__global__ __launch_bounds__(256, 2)
void fused_kernel(const float* __restrict__ x, float* __restrict__ out) {
    __shared__ __attribute__((aligned(16))) uint16_t sA[68 * CH];   // 34816 B
    __shared__ __attribute__((aligned(16))) uint16_t sX[CH * SXS];  // 36864 B

    const int tid  = threadIdx.x;
    const int lane = tid & 63;
    const int wid  = tid >> 6;
    const int b    = blockIdx.y;
    const int t0   = blockIdx.x * TN;

    const float* __restrict__ xb = x + (size_t)b * CH * TLEN;

    // ---- main staging pass: rows ti = 0..63 (gt = t0-2+lane, t-local = lane-2) ----
    {
        const int gt = t0 - 2 + lane;
        const int tl = lane - 2;
        const int c0 = wid * 64;
#pragma unroll
        for (int g = 0; g < 8; ++g) {
            const int cb = c0 + g * 8;
            const float* xp = xb + (size_t)cb * TLEN + gt;
            bf16x8 pk;
            uint16_t px[8];
#pragma unroll
            for (int j = 0; j < 8; ++j) {
                float v;
                if (blockIdx.x > 0) v = xp[(size_t)j * TLEN];
                else                v = (gt >= 0) ? xp[(size_t)j * TLEN] : 0.0f;
                px[j] = f32_to_bf16(v);
                pk[j] = (short)f32_to_bf16(gelu_fast(v));
            }
            *(bf16x8*)(&sA[lane * CH + (cb ^ ((lane & 7) << 3))]) = pk;
            if (tl >= 0) {
#pragma unroll
                for (int j = 0; j < 8; ++j) sX[(cb + j) * SXS + tl] = px[j];
            }
        }
    }
    // ---- halo pass: sA rows ti = 64..67 (gt = t0+62..t0+65), c = tid; sX t=62,63 ----
    {
        const int c = tid;
#pragma unroll
        for (int k = 0; k < 4; ++k) {
            const int gt = t0 + 62 + k;
            float v;
            if (blockIdx.x < gridDim.x - 1) v = xb[(size_t)c * TLEN + gt];
            else                            v = (gt < TLEN) ? xb[(size_t)c * TLEN + gt] : 0.0f;
            sA[(64 + k) * CH + (c ^ (k << 3))] = f32_to_bf16(gelu_fast(v));
            if (k < 2) sX[c * SXS + 62 + k] = f32_to_bf16(v);
        }
    }
    __syncthreads();

    f32x4 acc[4][4];
    const f32x4 vzero = {0.f, 0.f, 0.f, 0.f};
#pragma unroll
    for (int mi = 0; mi < 4; ++mi)
#pragma unroll
        for (int ni = 0; ni < 4; ++ni) acc[mi][ni] = vzero;

    const int m0   = wid * 64;
    const int kgrp = (lane >> 4) * 8;  // k sub-offset per 16-lane group

    // K loop, 1-deep software pipeline. Weights from global (L2), a from LDS.
    bf16x8 afb[2][4], bfb[2][4];
#pragma unroll
    for (int mi = 0; mi < 4; ++mi) {
        const int co = m0 + mi * 16 + (lane & 15);
        afb[0][mi] = *(const bf16x8*)(g_w1eff + co * CH + kgrp);
    }
#pragma unroll
    for (int ni = 0; ni < 4; ++ni) {
        const int tr = ni * 16 + (lane & 15) + 2;
        bfb[0][ni] = *(const bf16x8*)(&sA[tr * CH + (kgrp ^ ((tr & 7) << 3))]);
    }
#pragma unroll
    for (int s = 0; s < 8; ++s) {
        const int cur = s & 1, nxt = cur ^ 1;
        if (s < 7) {
            const int kk = (s + 1) * 32;
#pragma unroll
            for (int mi = 0; mi < 4; ++mi) {
                const int co = m0 + mi * 16 + (lane & 15);
                afb[nxt][mi] = *(const bf16x8*)(g_w1eff + co * CH + kk + kgrp);
            }
            const int cin = kk + kgrp;
#pragma unroll
            for (int ni = 0; ni < 4; ++ni) {
                const int tr = ni * 16 + (lane & 15) + 2;
                bfb[nxt][ni] = *(const bf16x8*)(&sA[tr * CH + (cin ^ ((tr & 7) << 3))]);
            }
        }
#pragma unroll
        for (int mi = 0; mi < 4; ++mi)
#pragma unroll
            for (int ni = 0; ni < 4; ++ni)
                acc[mi][ni] = __builtin_amdgcn_mfma_f32_16x16x32_bf16(afb[cur][mi], bfb[cur][ni], acc[mi][ni], 0, 0, 0);
    }

    // Epilogue phase A: fold depthwise + bias into acc (in-register).
    // MFMA D layout: col(t) = lane&15, row(c) = (lane>>4)*4 + reg.
    const int colt = lane & 15;
    const int rg   = (lane >> 4) * 4;
#pragma unroll
    for (int mi = 0; mi < 4; ++mi) {
        const int c = m0 + mi * 16 + rg;           // 4 channels c..c+3, 4-aligned
        const f32x4 tp0 = *(const f32x4*)(g_tap + 0 * CH + c);
        const f32x4 tp1 = *(const f32x4*)(g_tap + 1 * CH + c);
        const f32x4 tp2 = *(const f32x4*)(g_tap + 2 * CH + c);
        const f32x4 tp3 = *(const f32x4*)(g_tap + 3 * CH + c);
        const f32x4 tp4 = *(const f32x4*)(g_tap + 4 * CH + c);
        const f32x4 bsv = *(const f32x4*)(g_bias + c);
#pragma unroll
        for (int ni = 0; ni < 4; ++ni) {
            const int t = ni * 16 + colt;          // tile-local time
            u16x4 a0 = *(const u16x4*)(&sA[(t + 0) * CH + (c ^ (((t + 0) & 7) << 3))]);
            u16x4 a1 = *(const u16x4*)(&sA[(t + 1) * CH + (c ^ (((t + 1) & 7) << 3))]);
            u16x4 a2 = *(const u16x4*)(&sA[(t + 2) * CH + (c ^ (((t + 2) & 7) << 3))]);
            u16x4 a3 = *(const u16x4*)(&sA[(t + 3) * CH + (c ^ (((t + 3) & 7) << 3))]);
            u16x4 a4 = *(const u16x4*)(&sA[(t + 4) * CH + (c ^ (((t + 4) & 7) << 3))]);
#pragma unroll
            for (int r = 0; r < 4; ++r) {
                float d = tp0[r] * bf16_to_f32(a0[r]);
                d = fmaf(tp1[r], bf16_to_f32(a1[r]), d);
                d = fmaf(tp2[r], bf16_to_f32(a2[r]), d);
                d = fmaf(tp3[r], bf16_to_f32(a3[r]), d);
                d = fmaf(tp4[r], bf16_to_f32(a4[r]), d);
                acc[mi][ni][r] += d + bsv[r];
            }
        }
    }
    __syncthreads();   // all sA reads done block-wide; sA becomes f32 scratch

    // Epilogue phase B: wave-private transpose through sA's storage; residual from sX.
    float* __restrict__ sS = ((float*)sA) + wid * (16 * 68);   // 4.25 KB per wave
    float* __restrict__ ob = out + (size_t)b * CH * TLEN;
    const int ci = lane >> 2;          // 0..15 channel-local
    const int q  = lane & 3;           // 0..3 t-quad (16 t each)

#pragma unroll
    for (int mi = 0; mi < 4; ++mi) {
#pragma unroll
        for (int ni = 0; ni < 4; ++ni) {
            const int t = ni * 16 + colt;
#pragma unroll
            for (int r = 0; r < 4; ++r) sS[(rg + r) * 68 + t] = acc[mi][ni][r];
        }
        const int cc = m0 + mi * 16 + ci;
        float* orow = ob + (size_t)cc * TLEN + t0 + q * 16;
        const float* srow = sS + ci * 68 + q * 16;
        f32x4 s0 = *(const f32x4*)(srow + 0);
        f32x4 s1 = *(const f32x4*)(srow + 4);
        f32x4 s2 = *(const f32x4*)(srow + 8);
        f32x4 s3 = *(const f32x4*)(srow + 12);
        const uint32_t* xw = (const uint32_t*)(&sX[cc * SXS + q * 16]);  // 8 u32 = 16 bf16
        f32x4 o0, o1, o2, o3;
        o0[0] = s0[0] + __builtin_bit_cast(float, xw[0] << 16);
        o0[1] = s0[1] + __builtin_bit_cast(float, xw[0] & 0xFFFF0000u);
        o0[2] = s0[2] + __builtin_bit_cast(float, xw[1] << 16);
        o0[3] = s0[3] + __builtin_bit_cast(float, xw[1] & 0xFFFF0000u);
        o1[0] = s1[0] + __builtin_bit_cast(float, xw[2] << 16);
        o1[1] = s1[1] + __builtin_bit_cast(float, xw[2] & 0xFFFF0000u);
        o1[2] = s1[2] + __builtin_bit_cast(float, xw[3] << 16);
        o1[3] = s1[3] + __builtin_bit_cast(float, xw[3] & 0xFFFF0000u);
        o2[0] = s2[0] + __builtin_bit_cast(float, xw[4] << 16);
        o2[1] = s2[1] + __builtin_bit_cast(float, xw[4] & 0xFFFF0000u);
        o2[2] = s2[2] + __builtin_bit_cast(float, xw[5] << 16);
        o2[3] = s2[3] + __builtin_bit_cast(float, xw[5] & 0xFFFF0000u);
        o3[0] = s3[0] + __builtin_bit_cast(float, xw[6] << 16);
        o3[1] = s3[1] + __builtin_bit_cast(float, xw[6] & 0xFFFF0000u);
        o3[2] = s3[2] + __builtin_bit_cast(float, xw[7] << 16);
        o3[3] = s3[3] + __builtin_bit_cast(float, xw[7] & 0xFFFF0000u);
        *(f32x4*)(orow + 0)  = o0;
        *(f32x4*)(orow + 4)  = o1;
        *(f32x4*)(orow + 8)  = o2;
        *(f32x4*)(orow + 12) = o3;
    }
}

extern "C" void kernel_launch(void* const* d_in, const int* in_sizes, int n_in,
                              void* d_out, int out_size, void* d_ws, size_t ws_size,
                              hipStream_t stream) {
    const float* x  = (const float*)d_in[0];
    const float* w1 = (const float*)d_in[1];
    const float* b1 = (const float*)d_in[2];
    const float* w3 = (const float*)d_in[3];
    const float* b3 = (const float*)d_in[4];
    const float* w5 = (const float*)d_in[5];
    const float* b5 = (const float*)d_in[6];
    const float* wc = (const float*)d_in[7];
    const float* bc = (const float*)d_in[8];
    float* out = (float*)d_out;

    prep_kernel<<<dim3(CH), dim3(CH), 0, stream>>>(w1, b1, w3, b3, w5, b5, wc, bc);
    fused_kernel<<<dim3(TLEN / TN, BATCH), dim3(256), 0, stream>>>(x, out);
}

// Round 10
// 129.446 us; speedup vs baseline: 1.0368x; 1.0025x over previous
//
#include <hip/hip_runtime.h>
#include <stdint.h>

#define BATCH 32
#define CH    256
#define TLEN  4096
#define TN    32
#define NROW  36            // sA rows: 32 main + 4 halo
#define SST   36            // phase-B f32 scratch row stride (144 B, 16B aligned)

typedef short    bf16x8 __attribute__((ext_vector_type(8)));
typedef float    f32x4  __attribute__((ext_vector_type(4)));
typedef uint16_t u16x4  __attribute__((ext_vector_type(4)));

__device__ __attribute__((aligned(16))) uint16_t g_w1eff[CH * CH];
__device__ __attribute__((aligned(16))) float g_tap[5 * CH];   // tap-major
__device__ __attribute__((aligned(16))) float g_bias[CH];

static __device__ __forceinline__ uint16_t f32_to_bf16(float f) {
    uint32_t u = __builtin_bit_cast(uint32_t, f);
    u += 0x7FFFu + ((u >> 16) & 1u);
    return (uint16_t)(u >> 16);
}
static __device__ __forceinline__ float bf16_to_f32(uint16_t h) {
    uint32_t u = ((uint32_t)h) << 16;
    return __builtin_bit_cast(float, u);
}
// tanh-form gelu folded into exp2: gelu ~= x - x / (1 + 2^(x*(A + B*x^2)))
static __device__ __forceinline__ float gelu_fast(float x) {
    const float A = 2.3022082f;
    const float B = 0.10294331f;
    float x2 = x * x;
    float z  = x * fmaf(x2, B, A);
    float e  = exp2f(z);
    float r  = __builtin_amdgcn_rcpf(1.0f + e);
    return fmaf(-x, r, x);
}

__global__ void prep_kernel(const float* __restrict__ w1, const float* __restrict__ b1,
                            const float* __restrict__ w3, const float* __restrict__ b3,
                            const float* __restrict__ w5, const float* __restrict__ b5,
                            const float* __restrict__ wc, const float* __restrict__ bc) {
    const int o = blockIdx.x;
    const int c = threadIdx.x;
    const float wc0 = wc[o * 3 + 0];
    g_w1eff[o * CH + c] = f32_to_bf16(wc0 * w1[o * CH + c]);
    if (c == 0) {
        const float wc1 = wc[o * 3 + 1], wc2 = wc[o * 3 + 2];
        g_tap[0 * CH + o] = wc2 * w5[o * 5 + 0];
        g_tap[1 * CH + o] = wc1 * w3[o * 3 + 0] + wc2 * w5[o * 5 + 1];
        g_tap[2 * CH + o] = wc1 * w3[o * 3 + 1] + wc2 * w5[o * 5 + 2];
        g_tap[3 * CH + o] = wc1 * w3[o * 3 + 2] + wc2 * w5[o * 5 + 3];
        g_tap[4 * CH + o] = wc2 * w5[o * 5 + 4];
        g_bias[o] = wc0 * b1[o] + wc1 * b3[o] + wc2 * b5[o] + bc[o];
    }
}

// Per block = one (batch b, 32-timestep tile).
// sA: gelu(x) [row=0..35][c] bf16, XOR-swizzled; rows 2..33 = t0..t0+31,
//     rows 0,1 = t0-2,t0-1 (left halo), rows 34,35 = t0+32,t0+33 (right halo).
// sX: bf16(x) [c][t=0..31], main range only (residual read in phase B).
// Staging is f32x4-vectorized (lane = (channel, t-quad)) for memory-level
// parallelism; halo staged in a tiny scalar pass.
__global__ __launch_bounds__(256, 4)
void fused_kernel(const float* __restrict__ x, float* __restrict__ out) {
    __shared__ __attribute__((aligned(16))) uint16_t sA[NROW * CH];  // 18432 B
    __shared__ __attribute__((aligned(16))) uint16_t sX[CH * TN];    // 16384 B

    const int tid  = threadIdx.x;
    const int lane = tid & 63;
    const int wid  = tid >> 6;
    const int b    = blockIdx.y;
    const int t0   = blockIdx.x * TN;

    const float* __restrict__ xb = x + (size_t)b * CH * TLEN;

    // ---- main staging: lane = (cs = lane>>3, q = lane&7); t = q*4..q*4+3 ----
    {
        const int cs = lane >> 3;
        const int q  = lane & 7;
        const int c0 = wid * 64;
        f32x4 v[8];
#pragma unroll
        for (int r = 0; r < 8; ++r) {
            const int c = c0 + r * 8 + cs;
            v[r] = *(const f32x4*)(xb + (size_t)c * TLEN + t0 + q * 4);
        }
#pragma unroll
        for (int r = 0; r < 8; ++r) {
            const int c = c0 + r * 8 + cs;
            u16x4 xr;
#pragma unroll
            for (int j = 0; j < 4; ++j) {
                const int row = q * 4 + j + 2;
                sA[row * CH + (c ^ ((row & 7) << 3))] = f32_to_bf16(gelu_fast(v[r][j]));
                xr[j] = f32_to_bf16(v[r][j]);
            }
            *(u16x4*)(&sX[c * TN + q * 4]) = xr;
        }
    }
    // ---- halo: rows {0,1,34,35} <-> gt {t0-2, t0-1, t0+32, t0+33}, c = tid ----
    {
        const int c = tid;
        const int gts[4] = {t0 - 2, t0 - 1, t0 + TN, t0 + TN + 1};
        const int ris[4] = {0, 1, 34, 35};
        const bool lo = (blockIdx.x == 0), hi = (blockIdx.x == gridDim.x - 1);
#pragma unroll
        for (int k = 0; k < 4; ++k) {
            const int gt = gts[k];
            float vv = 0.0f;
            if ((!lo || gt >= 0) && (!hi || gt < TLEN)) vv = xb[(size_t)c * TLEN + gt];
            const int ri = ris[k];
            sA[ri * CH + (c ^ ((ri & 7) << 3))] = f32_to_bf16(gelu_fast(vv));
        }
    }
    __syncthreads();

    f32x4 acc[4][2];
    const f32x4 vzero = {0.f, 0.f, 0.f, 0.f};
#pragma unroll
    for (int mi = 0; mi < 4; ++mi)
#pragma unroll
        for (int ni = 0; ni < 2; ++ni) acc[mi][ni] = vzero;

    const int m0   = wid * 64;
    const int kgrp = (lane >> 4) * 8;

    // K loop, 1-deep software pipeline. Weights from global (L2), a from LDS.
    bf16x8 afb[2][4], bfb[2][2];
#pragma unroll
    for (int mi = 0; mi < 4; ++mi) {
        const int co = m0 + mi * 16 + (lane & 15);
        afb[0][mi] = *(const bf16x8*)(g_w1eff + co * CH + kgrp);
    }
#pragma unroll
    for (int ni = 0; ni < 2; ++ni) {
        const int tr = ni * 16 + (lane & 15) + 2;
        bfb[0][ni] = *(const bf16x8*)(&sA[tr * CH + (kgrp ^ ((tr & 7) << 3))]);
    }
#pragma unroll
    for (int s = 0; s < 8; ++s) {
        const int cur = s & 1, nxt = cur ^ 1;
        if (s < 7) {
            const int kk = (s + 1) * 32;
#pragma unroll
            for (int mi = 0; mi < 4; ++mi) {
                const int co = m0 + mi * 16 + (lane & 15);
                afb[nxt][mi] = *(const bf16x8*)(g_w1eff + co * CH + kk + kgrp);
            }
            const int cin = kk + kgrp;
#pragma unroll
            for (int ni = 0; ni < 2; ++ni) {
                const int tr = ni * 16 + (lane & 15) + 2;
                bfb[nxt][ni] = *(const bf16x8*)(&sA[tr * CH + (cin ^ ((tr & 7) << 3))]);
            }
        }
#pragma unroll
        for (int mi = 0; mi < 4; ++mi)
#pragma unroll
            for (int ni = 0; ni < 2; ++ni)
                acc[mi][ni] = __builtin_amdgcn_mfma_f32_16x16x32_bf16(afb[cur][mi], bfb[cur][ni], acc[mi][ni], 0, 0, 0);
    }

    // Phase A: fold depthwise + bias into acc. D layout: col(t)=lane&15, row(c)=(lane>>4)*4+reg.
    const int colt = lane & 15;
    const int rg   = (lane >> 4) * 4;
#pragma unroll
    for (int mi = 0; mi < 4; ++mi) {
        const int c = m0 + mi * 16 + rg;
        const f32x4 tp0 = *(const f32x4*)(g_tap + 0 * CH + c);
        const f32x4 tp1 = *(const f32x4*)(g_tap + 1 * CH + c);
        const f32x4 tp2 = *(const f32x4*)(g_tap + 2 * CH + c);
        const f32x4 tp3 = *(const f32x4*)(g_tap + 3 * CH + c);
        const f32x4 tp4 = *(const f32x4*)(g_tap + 4 * CH + c);
        const f32x4 bsv = *(const f32x4*)(g_bias + c);
#pragma unroll
        for (int ni = 0; ni < 2; ++ni) {
            const int t = ni * 16 + colt;          // tile-local time; sA row = t+2
            u16x4 a0 = *(const u16x4*)(&sA[(t + 0) * CH + (c ^ (((t + 0) & 7) << 3))]);
            u16x4 a1 = *(const u16x4*)(&sA[(t + 1) * CH + (c ^ (((t + 1) & 7) << 3))]);
            u16x4 a2 = *(const u16x4*)(&sA[(t + 2) * CH + (c ^ (((t + 2) & 7) << 3))]);
            u16x4 a3 = *(const u16x4*)(&sA[(t + 3) * CH + (c ^ (((t + 3) & 7) << 3))]);
            u16x4 a4 = *(const u16x4*)(&sA[(t + 4) * CH + (c ^ (((t + 4) & 7) << 3))]);
#pragma unroll
            for (int r = 0; r < 4; ++r) {
                float d = tp0[r] * bf16_to_f32(a0[r]);
                d = fmaf(tp1[r], bf16_to_f32(a1[r]), d);
                d = fmaf(tp2[r], bf16_to_f32(a2[r]), d);
                d = fmaf(tp3[r], bf16_to_f32(a3[r]), d);
                d = fmaf(tp4[r], bf16_to_f32(a4[r]), d);
                acc[mi][ni][r] += d + bsv[r];
            }
        }
    }
    __syncthreads();   // all sA reads done; sA storage becomes f32 scratch

    // Phase B: wave-private transpose through sA's storage; residual from sX.
    float* __restrict__ sS = ((float*)sA) + wid * (16 * SST);   // 2304 B per wave
    float* __restrict__ ob = out + (size_t)b * CH * TLEN;
    const int ci = lane >> 2;          // 0..15 channel-local
    const int q  = lane & 3;           // 0..3 -> t = q*8 .. q*8+7

#pragma unroll
    for (int mi = 0; mi < 4; ++mi) {
#pragma unroll
        for (int ni = 0; ni < 2; ++ni) {
            const int t = ni * 16 + colt;
#pragma unroll
            for (int r = 0; r < 4; ++r) sS[(rg + r) * SST + t] = acc[mi][ni][r];
        }
        const int cc = m0 + mi * 16 + ci;
        float* orow = ob + (size_t)cc * TLEN + t0 + q * 8;
        const float* srow = sS + ci * SST + q * 8;
        f32x4 s0 = *(const f32x4*)(srow + 0);
        f32x4 s1 = *(const f32x4*)(srow + 4);
        const uint32_t* xw = (const uint32_t*)(&sX[cc * TN + q * 8]);  // 4 u32 = 8 bf16
        f32x4 o0, o1;
        o0[0] = s0[0] + __builtin_bit_cast(float, xw[0] << 16);
        o0[1] = s0[1] + __builtin_bit_cast(float, xw[0] & 0xFFFF0000u);
        o0[2] = s0[2] + __builtin_bit_cast(float, xw[1] << 16);
        o0[3] = s0[3] + __builtin_bit_cast(float, xw[1] & 0xFFFF0000u);
        o1[0] = s1[0] + __builtin_bit_cast(float, xw[2] << 16);
        o1[1] = s1[1] + __builtin_bit_cast(float, xw[2] & 0xFFFF0000u);
        o1[2] = s1[2] + __builtin_bit_cast(float, xw[3] << 16);
        o1[3] = s1[3] + __builtin_bit_cast(float, xw[3] & 0xFFFF0000u);
        *(f32x4*)(orow + 0) = o0;
        *(f32x4*)(orow + 4) = o1;
    }
}

extern "C" void kernel_launch(void* const* d_in, const int* in_sizes, int n_in,
                              void* d_out, int out_size, void* d_ws, size_t ws_size,
                              hipStream_t stream) {
    const float* x  = (const float*)d_in[0];
    const float* w1 = (const float*)d_in[1];
    const float* b1 = (const float*)d_in[2];
    const float* w3 = (const float*)d_in[3];
    const float* b3 = (const float*)d_in[4];
    const float* w5 = (const float*)d_in[5];
    const float* b5 = (const float*)d_in[6];
    const float* wc = (const float*)d_in[7];
    const float* bc = (const float*)d_in[8];
    float* out = (float*)d_out;

    prep_kernel<<<dim3(CH), dim3(CH), 0, stream>>>(w1, b1, w3, b3, w5, b5, wc, bc);
    fused_kernel<<<dim3(TLEN / TN, BATCH), dim3(256), 0, stream>>>(x, out);
}